// Round 2
// baseline (659.266 us; speedup 1.0000x reference)
//
#include <hip/hip_runtime.h>
#include <stdint.h>

typedef unsigned short u16;
typedef short bf16x8 __attribute__((ext_vector_type(8)));
typedef short bf16x4 __attribute__((ext_vector_type(4)));
typedef float f32x4 __attribute__((ext_vector_type(4)));
typedef u16 u16x8 __attribute__((ext_vector_type(8)));
typedef u16 u16x4 __attribute__((ext_vector_type(4)));

#define NHEADS 8
#define SEQ 1024
#define DM 512
#define DEPTH 64
#define BATCH 8

__device__ __forceinline__ u16 f2bf(float f) {
    union { float f; unsigned u; } v; v.f = f;
    unsigned r = v.u + 0x7FFF + ((v.u >> 16) & 1);
    return (u16)(r >> 16);
}

// 16x16x16 bf16 MFMA: A lane holds m=lane&15, k=(lane>>4)*4+j  -> P-fragment
// is lane-local after swapped QK^T. Builtin if present, else inline asm.
__device__ __forceinline__ f32x4 mfma_16x16x16_bf16(bf16x4 a, bf16x4 b, f32x4 c) {
#if __has_builtin(__builtin_amdgcn_mfma_f32_16x16x16bf16_1k)
    return __builtin_amdgcn_mfma_f32_16x16x16bf16_1k(a, b, c, 0, 0, 0);
#else
    asm("v_mfma_f32_16x16x16_bf16 %0, %1, %2, %0" : "+v"(c) : "v"(a), "v"(b));
    return c;
#endif
}

// ---------------------------------------------------------------- prep
__global__ void __launch_bounds__(256) transpose512(
    const float* __restrict__ w0, const float* __restrict__ w1,
    const float* __restrict__ w2, const float* __restrict__ w3,
    u16* __restrict__ wt)
{
    __shared__ float tile[32][33];
    const float* w = (blockIdx.z == 0) ? w0 : (blockIdx.z == 1) ? w1
                   : (blockIdx.z == 2) ? w2 : w3;
    u16* o = wt + (size_t)blockIdx.z * (DM * DM);
    int rb = blockIdx.y * 32, cb = blockIdx.x * 32;
    int tx = threadIdx.x, ty = threadIdx.y;  // 32 x 8
    #pragma unroll
    for (int k = 0; k < 32; k += 8)
        tile[ty + k][tx] = w[(size_t)(rb + ty + k) * DM + cb + tx];
    __syncthreads();
    #pragma unroll
    for (int k = 0; k < 32; k += 8)
        o[(size_t)(cb + ty + k) * DM + rb + tx] = f2bf(tile[tx][ty + k]);
}

__global__ void __launch_bounds__(256) conv_bf16(
    const float* __restrict__ q, const float* __restrict__ k,
    const float* __restrict__ v,
    u16* __restrict__ oq, u16* __restrict__ ok, u16* __restrict__ ov)
{
    const float* src = (blockIdx.z == 0) ? q : (blockIdx.z == 1) ? k : v;
    u16* dst = (blockIdx.z == 0) ? oq : (blockIdx.z == 1) ? ok : ov;
    size_t i = ((size_t)blockIdx.x * 256 + threadIdx.x) * 8;
    f32x4 a = *(const f32x4*)(src + i);
    f32x4 b = *(const f32x4*)(src + i + 4);
    u16x8 o;
    #pragma unroll
    for (int j = 0; j < 4; j++) { o[j] = f2bf(a[j]); o[j + 4] = f2bf(b[j]); }
    *(u16x8*)(dst + i) = o;
}

// ---------------------------------------------------------------- GEMM core
template <int LAYOUT>
__device__ __forceinline__ void gemm_tile(
    const u16* __restrict__ A, const u16* __restrict__ wt,
    const float* __restrict__ bias, void* __restrict__ out_)
{
    const int tid = threadIdx.x;
    const int wid = tid >> 6, lane = tid & 63;
    const int wm = wid >> 1, wn = wid & 1;
    const int mb = blockIdx.y * 128 + wm * 64;
    const int nb = blockIdx.x * 128 + wn * 64;
    const int lr = lane & 15, g = lane >> 4, lk = g * 8;

    f32x4 acc[4][4];
    #pragma unroll
    for (int i = 0; i < 4; i++)
        #pragma unroll
        for (int j = 0; j < 4; j++) acc[i][j] = (f32x4)0.f;

    for (int ks = 0; ks < DM; ks += 32) {
        bf16x8 a[4], bf[4];
        #pragma unroll
        for (int mt = 0; mt < 4; mt++)
            a[mt] = *(const bf16x8*)(A + (size_t)(mb + mt * 16 + lr) * DM + ks + lk);
        #pragma unroll
        for (int nt = 0; nt < 4; nt++)
            bf[nt] = *(const bf16x8*)(wt + (size_t)(nb + nt * 16 + lr) * DM + ks + lk);
        #pragma unroll
        for (int mt = 0; mt < 4; mt++)
            #pragma unroll
            for (int nt = 0; nt < 4; nt++) {
                if (LAYOUT == 1)
                    acc[mt][nt] = __builtin_amdgcn_mfma_f32_16x16x32_bf16(
                        bf[nt], a[mt], acc[mt][nt], 0, 0, 0);
                else
                    acc[mt][nt] = __builtin_amdgcn_mfma_f32_16x16x32_bf16(
                        a[mt], bf[nt], acc[mt][nt], 0, 0, 0);
            }
    }

    #pragma unroll
    for (int mt = 0; mt < 4; mt++) {
        #pragma unroll
        for (int nt = 0; nt < 4; nt++) {
            #pragma unroll
            for (int r = 0; r < 4; r++) {
                if (LAYOUT == 1) {
                    int m = mb + mt * 16 + lr;
                    int n = nb + nt * 16 + 4 * g + r;
                    float val = acc[mt][nt][r] + bias[n];
                    int b_ = m >> 10, s = m & 1023, h = n >> 6, d = n & 63;
                    ((u16*)out_)[((size_t)((b_ * NHEADS + h) << 6) + d) * SEQ + s] = f2bf(val);
                } else {
                    int n = nb + nt * 16 + lr;
                    int m = mb + mt * 16 + 4 * g + r;
                    float val = acc[mt][nt][r] + bias[n];
                    if (LAYOUT == 2) {
                        ((float*)out_)[(size_t)m * DM + n] = val;
                    } else {
                        int b_ = m >> 10, s = m & 1023, h = n >> 6, d = n & 63;
                        ((u16*)out_)[(((size_t)(b_ * NHEADS + h) * SEQ + s) << 6) + d] = f2bf(val);
                    }
                }
            }
        }
    }
}

__global__ void __launch_bounds__(256) qkv_proj(
    const u16* __restrict__ qbf, const u16* __restrict__ kbf,
    const u16* __restrict__ vbf, const u16* __restrict__ wt_base,
    const float* __restrict__ bq, const float* __restrict__ bk,
    const float* __restrict__ bv,
    u16* __restrict__ Qb, u16* __restrict__ Kb, u16* __restrict__ VTb)
{
    int z = blockIdx.z;
    if (z == 0)      gemm_tile<0>(qbf, wt_base,               bq, Qb);
    else if (z == 1) gemm_tile<0>(kbf, wt_base + DM * DM,     bk, Kb);
    else             gemm_tile<1>(vbf, wt_base + 2 * DM * DM, bv, VTb);
}

__global__ void __launch_bounds__(256) out_proj(
    const u16* __restrict__ X, const u16* __restrict__ wto,
    const float* __restrict__ bo, float* __restrict__ out)
{
    gemm_tile<2>(X, wto, bo, out);
}

// ---------------------------------------------------------------- attention
// k-stripe mapping: acc[nt][r] = S[q=lr][k = nt*64 + wid*16 + 4g + r].
// PV uses 16x16x16 MFMA so the A-operand (P) is the lane's own converted acc:
// NO LDS stash, no ds_read, no cross-lane. Each wave computes a partial X
// over its own 256 k; one 16KB LDS reduction combines the 4 waves.
__global__ void __launch_bounds__(256, 5) attn_kernel(
    const u16* __restrict__ Q, const u16* __restrict__ K,
    const u16* __restrict__ VT, const float* __restrict__ mask,
    const float* __restrict__ addw, float* __restrict__ attn_out,
    u16* __restrict__ X)
{
    __shared__ float Xr[4][16][64];   // 16 KB
    __shared__ float redm[4][16];
    __shared__ float reds[4][16];

    // bijective remap: all 8 h-blocks of one (b,qt) share id%8 -> same XCD
    const int id = blockIdx.x;
    const int c = id & 7, t = id >> 3;
    const int h = t & 7;
    const int p = ((t >> 3) << 3) | c;
    const int qt = p & 63, b = p >> 6;

    const int tid = threadIdx.x, wid = tid >> 6, lane = tid & 63;
    const int lr = lane & 15, g = lane >> 4, lk = g * 8;
    const size_t head = (size_t)(b * NHEADS + h) * (SEQ * DEPTH);
    const u16* Qh = Q + head + (size_t)qt * 16 * DEPTH;
    const u16* Kh = K + head;
    const u16* Vh = VT + head;            // [64][1024] bf16
    const int kst = (wid << 4) + (g << 2);  // lane's k offset within 64-stripe

    // ---- phase 1: S = K @ Q^T (transposed acc)
    bf16x8 qf0 = *(const bf16x8*)(Qh + lr * DEPTH + lk);
    bf16x8 qf1 = *(const bf16x8*)(Qh + lr * DEPTH + 32 + lk);
    f32x4 acc[16];
    #pragma unroll
    for (int nt = 0; nt < 16; nt++) acc[nt] = (f32x4)0.f;
    #pragma unroll
    for (int nt = 0; nt < 16; nt++) {
        const u16* kp = Kh + (size_t)(nt * 64 + (wid << 4) + lr) * DEPTH + lk;
        bf16x8 k0 = *(const bf16x8*)kp;
        bf16x8 k1 = *(const bf16x8*)(kp + 32);
        acc[nt] = __builtin_amdgcn_mfma_f32_16x16x32_bf16(k0, qf0, acc[nt], 0, 0, 0);
        acc[nt] = __builtin_amdgcn_mfma_f32_16x16x32_bf16(k1, qf1, acc[nt], 0, 0, 0);
    }

    // ---- scale + mask + per-lane max
    const float* mrow = mask + ((size_t)b << 10);
    float mx = -3.0e38f;
    #pragma unroll
    for (int nt = 0; nt < 16; nt++) {
        f32x4 mr = *(const f32x4*)(mrow + nt * 64 + kst);
        #pragma unroll
        for (int r = 0; r < 4; r++) {
            acc[nt][r] = acc[nt][r] * 0.125f + mr[r] * -1e9f;
            mx = fmaxf(mx, acc[nt][r]);
        }
    }
    mx = fmaxf(mx, __shfl_xor(mx, 16, 64));
    mx = fmaxf(mx, __shfl_xor(mx, 32, 64));
    if (lane < 16) redm[wid][lr] = mx;
    __syncthreads();
    float gm = fmaxf(fmaxf(redm[0][lr], redm[1][lr]),
                     fmaxf(redm[2][lr], redm[3][lr]));

    // ---- exp + row sum
    float sm = 0.f;
    #pragma unroll
    for (int nt = 0; nt < 16; nt++)
        #pragma unroll
        for (int r = 0; r < 4; r++) {
            float pv = __expf(acc[nt][r] - gm);
            acc[nt][r] = pv;
            sm += pv;
        }
    sm += __shfl_xor(sm, 16, 64);
    sm += __shfl_xor(sm, 32, 64);
    if (lane < 16) reds[wid][lr] = sm;
    __syncthreads();
    float iv = 1.0f / (reds[0][lr] + reds[1][lr] + reds[2][lr] + reds[3][lr]);

    // ---- fused: addw * P -> attn store + lane-local PV (no barrier inside)
    const int qglob = (qt << 4) + lr;
    const size_t awbase = ((size_t)((b << 10) + qglob)) << 10;
    const size_t aobase = ((size_t)(((b * NHEADS + h) << 10) + qglob)) << 10;
    const u16* vb_base = Vh + (size_t)lr * SEQ;

    f32x4 x[4];
    #pragma unroll
    for (int dt = 0; dt < 4; dt++) x[dt] = (f32x4)0.f;

    #pragma unroll
    for (int nt = 0; nt < 16; nt++) {
        const int k0 = nt * 64 + kst;
        f32x4 aw = *(const f32x4*)(addw + awbase + k0);
        f32x4 o;
        bf16x4 pa;
        #pragma unroll
        for (int r = 0; r < 4; r++) {
            float v = acc[nt][r] * iv * aw[r];
            o[r] = v;
            pa[r] = (short)f2bf(v);
        }
        *(f32x4*)(attn_out + aobase + k0) = o;
        #pragma unroll
        for (int dt = 0; dt < 4; dt++) {
            bf16x4 vb = *(const bf16x4*)(vb_base + (size_t)(dt << 4) * SEQ + k0);
            x[dt] = mfma_16x16x16_bf16(pa, vb, x[dt]);
        }
    }

    // ---- cross-wave X reduction: partial X[q=4g+r][d=dt*16+lr] per wave
    #pragma unroll
    for (int dt = 0; dt < 4; dt++)
        #pragma unroll
        for (int r = 0; r < 4; r++)
            Xr[wid][4 * g + r][(dt << 4) + lr] = x[dt][r];
    __syncthreads();

    #pragma unroll
    for (int r = 0; r < 4; r++) {
        int q = 4 * g + r, d = (wid << 4) + lr;
        float s = Xr[0][q][d] + Xr[1][q][d] + Xr[2][q][d] + Xr[3][q][d];
        X[((size_t)((b << 10) + (qt << 4) + q)) * DM + (h << 6) + d] = f2bf(s);
    }
}

// ---------------------------------------------------------------- launch
extern "C" void kernel_launch(void* const* d_in, const int* in_sizes, int n_in,
                              void* d_out, int out_size, void* d_ws, size_t ws_size,
                              hipStream_t stream)
{
    const float* q_in = (const float*)d_in[0];
    const float* k_in = (const float*)d_in[1];
    const float* v_in = (const float*)d_in[2];
    const float* mask = (const float*)d_in[3];
    const float* addw = (const float*)d_in[4];
    const float* wq = (const float*)d_in[5];
    const float* bq = (const float*)d_in[6];
    const float* wk = (const float*)d_in[7];
    const float* bk = (const float*)d_in[8];
    const float* wv = (const float*)d_in[9];
    const float* bv = (const float*)d_in[10];
    const float* wo = (const float*)d_in[11];
    const float* bo = (const float*)d_in[12];

    const size_t ACT = (size_t)BATCH * SEQ * DM;   // 4,194,304 elements

    u16* ws = (u16*)d_ws;
    u16* wt  = ws;                    // 4 * 512*512 bf16      (2 MB)
    u16* Qb  = wt + 4 * DM * DM;      // [B,H,S,D] bf16        (8 MB)
    u16* Kb  = Qb + ACT;              // [B,H,S,D] bf16        (8 MB)
    u16* VTb = Kb + ACT;              // [B,H,D,S] bf16        (8 MB)
    u16* Xb  = VTb + ACT;             // [B,S,DM]  bf16        (8 MB)

    float* out0 = (float*)d_out;                         // [B,S,512] f32
    float* attn_out = out0 + ACT;                        // [B,H,S,S] f32 (268 MB)

    // bf16 activations alias the attn_out region (overwritten later)
    u16* qbf = (u16*)attn_out;
    u16* kbf = qbf + ACT;
    u16* vbf = kbf + ACT;

    transpose512<<<dim3(16, 16, 4), dim3(32, 8), 0, stream>>>(wq, wk, wv, wo, wt);
    conv_bf16<<<dim3(2048, 1, 3), 256, 0, stream>>>(q_in, k_in, v_in, qbf, kbf, vbf);
    qkv_proj<<<dim3(4, 64, 3), 256, 0, stream>>>(qbf, kbf, vbf, wt, bq, bk, bv,
                                                 Qb, Kb, VTb);
    attn_kernel<<<dim3(4096), 256, 0, stream>>>(Qb, Kb, VTb, mask, addw,
                                                attn_out, Xb);
    out_proj<<<dim3(4, 64, 1), 256, 0, stream>>>(Xb, wt + 3 * DM * DM, bo, out0);
}

// Round 3
// 602.056 us; speedup vs baseline: 1.0950x; 1.0950x over previous
//
#include <hip/hip_runtime.h>
#include <stdint.h>

typedef unsigned short u16;
typedef short bf16x8 __attribute__((ext_vector_type(8)));
typedef short bf16x4 __attribute__((ext_vector_type(4)));
typedef float f32x4 __attribute__((ext_vector_type(4)));
typedef u16 u16x8 __attribute__((ext_vector_type(8)));
typedef u16 u16x4 __attribute__((ext_vector_type(4)));

#define NHEADS 8
#define SEQ 1024
#define DM 512
#define DEPTH 64
#define BATCH 8
#define BK 32
#define LDSROW 40   // 32 + 8 pad -> 80B row stride, even bank spread for b128

__device__ __forceinline__ u16 f2bf(float f) {
    union { float f; unsigned u; } v; v.f = f;
    unsigned r = v.u + 0x7FFF + ((v.u >> 16) & 1);
    return (u16)(r >> 16);
}

// 16x16x16 bf16 MFMA (P operand is lane-local after swapped QK^T)
__device__ __forceinline__ f32x4 mfma_16x16x16_bf16(bf16x4 a, bf16x4 b, f32x4 c) {
#if __has_builtin(__builtin_amdgcn_mfma_f32_16x16x16bf16_1k)
    return __builtin_amdgcn_mfma_f32_16x16x16bf16_1k(a, b, c, 0, 0, 0);
#else
    asm("v_mfma_f32_16x16x16_bf16 %0, %1, %2, %0" : "+v"(c) : "v"(a), "v"(b));
    return c;
#endif
}

// ---------------------------------------------------------------- prep
__global__ void __launch_bounds__(256) transpose512(
    const float* __restrict__ w0, const float* __restrict__ w1,
    const float* __restrict__ w2, const float* __restrict__ w3,
    u16* __restrict__ wt)
{
    __shared__ float tile[32][33];
    const float* w = (blockIdx.z == 0) ? w0 : (blockIdx.z == 1) ? w1
                   : (blockIdx.z == 2) ? w2 : w3;
    u16* o = wt + (size_t)blockIdx.z * (DM * DM);
    int rb = blockIdx.y * 32, cb = blockIdx.x * 32;
    int tx = threadIdx.x, ty = threadIdx.y;  // 32 x 8
    #pragma unroll
    for (int k = 0; k < 32; k += 8)
        tile[ty + k][tx] = w[(size_t)(rb + ty + k) * DM + cb + tx];
    __syncthreads();
    #pragma unroll
    for (int k = 0; k < 32; k += 8)
        o[(size_t)(cb + ty + k) * DM + rb + tx] = f2bf(tile[tx][ty + k]);
}

// ---------------------------------------------------------------- GEMM core
// Reg-staged, double-buffered LDS GEMM. 128x128 tile, BK=32, 4 waves 2x2.
// AF32=1: A is f32, converted to bf16 during staging (fuses the old conv_bf16).
// One barrier per K-step; prefetch loads issued before the barrier survive it
// (VGPR dest, no vmcnt drain at s_barrier).
template <int LAYOUT, int AF32>
__device__ __forceinline__ void gemm_tile2(
    const void* __restrict__ Asrc, const u16* __restrict__ wt,
    const float* __restrict__ bias, void* __restrict__ out_)
{
    __shared__ u16 Al[2][128 * LDSROW];
    __shared__ u16 Bl[2][128 * LDSROW];

    const int tid = threadIdx.x;
    const int wid = tid >> 6, lane = tid & 63;
    const int wm = wid >> 1, wn = wid & 1;
    const int lr = lane & 15, g = lane >> 4, lk = g * 8;
    const int mb = blockIdx.y * 128;
    const int nb = blockIdx.x * 128;
    const int r0 = tid >> 2;          // staging row 0..63
    const int c0 = (tid & 3) * 8;     // staging col chunk

    // staging registers
    f32x4 fa0a, fa0b, fa1a, fa1b;
    u16x8 ua0, ua1, ub0, ub1;

    auto loadStage = [&](int ks) {
        if (AF32) {
            const float* A = (const float*)Asrc;
            fa0a = *(const f32x4*)(A + (size_t)(mb + r0) * DM + ks + c0);
            fa0b = *(const f32x4*)(A + (size_t)(mb + r0) * DM + ks + c0 + 4);
            fa1a = *(const f32x4*)(A + (size_t)(mb + 64 + r0) * DM + ks + c0);
            fa1b = *(const f32x4*)(A + (size_t)(mb + 64 + r0) * DM + ks + c0 + 4);
        } else {
            const u16* A = (const u16*)Asrc;
            ua0 = *(const u16x8*)(A + (size_t)(mb + r0) * DM + ks + c0);
            ua1 = *(const u16x8*)(A + (size_t)(mb + 64 + r0) * DM + ks + c0);
        }
        ub0 = *(const u16x8*)(wt + (size_t)(nb + r0) * DM + ks + c0);
        ub1 = *(const u16x8*)(wt + (size_t)(nb + 64 + r0) * DM + ks + c0);
    };
    auto writeStage = [&](int buf) {
        u16x8 w0, w1;
        if (AF32) {
            #pragma unroll
            for (int j = 0; j < 4; j++) {
                w0[j] = f2bf(fa0a[j]); w0[j + 4] = f2bf(fa0b[j]);
                w1[j] = f2bf(fa1a[j]); w1[j + 4] = f2bf(fa1b[j]);
            }
        } else { w0 = ua0; w1 = ua1; }
        *(u16x8*)(&Al[buf][r0 * LDSROW + c0]) = w0;
        *(u16x8*)(&Al[buf][(64 + r0) * LDSROW + c0]) = w1;
        *(u16x8*)(&Bl[buf][r0 * LDSROW + c0]) = ub0;
        *(u16x8*)(&Bl[buf][(64 + r0) * LDSROW + c0]) = ub1;
    };

    f32x4 acc[4][4];
    #pragma unroll
    for (int i = 0; i < 4; i++)
        #pragma unroll
        for (int j = 0; j < 4; j++) acc[i][j] = (f32x4)0.f;

    loadStage(0);
    for (int ks = 0, step = 0; ks < DM; ks += BK, step++) {
        const int buf = step & 1;
        writeStage(buf);                       // waits vmcnt for its regs
        if (ks + BK < DM) loadStage(ks + BK);  // prefetch next (survives barrier)
        __syncthreads();

        bf16x8 af[4], bf4[4];
        #pragma unroll
        for (int mt = 0; mt < 4; mt++)
            af[mt] = *(const bf16x8*)(&Al[buf][(wm * 64 + mt * 16 + lr) * LDSROW + lk]);
        #pragma unroll
        for (int nt = 0; nt < 4; nt++)
            bf4[nt] = *(const bf16x8*)(&Bl[buf][(wn * 64 + nt * 16 + lr) * LDSROW + lk]);
        #pragma unroll
        for (int mt = 0; mt < 4; mt++)
            #pragma unroll
            for (int nt = 0; nt < 4; nt++) {
                if (LAYOUT == 1)
                    acc[mt][nt] = __builtin_amdgcn_mfma_f32_16x16x32_bf16(
                        bf4[nt], af[mt], acc[mt][nt], 0, 0, 0);
                else
                    acc[mt][nt] = __builtin_amdgcn_mfma_f32_16x16x32_bf16(
                        af[mt], bf4[nt], acc[mt][nt], 0, 0, 0);
            }
        // no second barrier: next overwrite of buf is 2 steps away, and the
        // next step's barrier (with lgkmcnt(0)) orders reads-before-writes.
    }

    #pragma unroll
    for (int mt = 0; mt < 4; mt++) {
        #pragma unroll
        for (int nt = 0; nt < 4; nt++) {
            #pragma unroll
            for (int r = 0; r < 4; r++) {
                if (LAYOUT == 1) {
                    int m = mb + wm * 64 + mt * 16 + lr;
                    int n = nb + wn * 64 + nt * 16 + 4 * g + r;
                    float val = acc[mt][nt][r] + bias[n];
                    int b_ = m >> 10, s = m & 1023, h = n >> 6, d = n & 63;
                    ((u16*)out_)[((size_t)((b_ * NHEADS + h) << 6) + d) * SEQ + s] = f2bf(val);
                } else {
                    int n = nb + wn * 64 + nt * 16 + lr;
                    int m = mb + wm * 64 + mt * 16 + 4 * g + r;
                    float val = acc[mt][nt][r] + bias[n];
                    if (LAYOUT == 2) {
                        ((float*)out_)[(size_t)m * DM + n] = val;
                    } else {
                        int b_ = m >> 10, s = m & 1023, h = n >> 6, d = n & 63;
                        ((u16*)out_)[(((size_t)(b_ * NHEADS + h) * SEQ + s) << 6) + d] = f2bf(val);
                    }
                }
            }
        }
    }
}

__global__ void __launch_bounds__(256) qkv_proj(
    const float* __restrict__ q_in, const float* __restrict__ k_in,
    const float* __restrict__ v_in, const u16* __restrict__ wt_base,
    const float* __restrict__ bq, const float* __restrict__ bk,
    const float* __restrict__ bv,
    u16* __restrict__ Qb, u16* __restrict__ Kb, u16* __restrict__ VTb)
{
    int z = blockIdx.z;
    if (z == 0)      gemm_tile2<0, 1>(q_in, wt_base,              bq, Qb);
    else if (z == 1) gemm_tile2<0, 1>(k_in, wt_base + DM * DM,    bk, Kb);
    else             gemm_tile2<1, 1>(v_in, wt_base + 2 * DM * DM, bv, VTb);
}

__global__ void __launch_bounds__(256) out_proj(
    const u16* __restrict__ X, const u16* __restrict__ wto,
    const float* __restrict__ bo, float* __restrict__ out)
{
    gemm_tile2<2, 0>(X, wto, bo, out);
}

// ---------------------------------------------------------------- attention
// Wave-contiguous k-stripes (kk = wid*256 + nt*16 + 4g) so a wave writes
// adjacent 64B line-halves on consecutive nt -> full-line merge, no L2 RMW.
// PV is lane-local via 16x16x16 MFMA (no P LDS round-trip); one 16KB LDS
// reduction combines the 4 waves' partial X.
__global__ void __launch_bounds__(256, 5) attn_kernel(
    const u16* __restrict__ Q, const u16* __restrict__ K,
    const u16* __restrict__ VT, const float* __restrict__ mask,
    const float* __restrict__ addw, float* __restrict__ attn_out,
    u16* __restrict__ X)
{
    __shared__ float Xr[4][16][64];   // 16 KB
    __shared__ float redm[4][16];
    __shared__ float reds[4][16];

    // bijective remap: all 8 h-blocks of one (b,qt) share id%8 -> same XCD
    const int id = blockIdx.x;
    const int c = id & 7, t = id >> 3;
    const int h = t & 7;
    const int p = ((t >> 3) << 3) | c;
    const int qt = p & 63, b = p >> 6;

    const int tid = threadIdx.x, wid = tid >> 6, lane = tid & 63;
    const int lr = lane & 15, g = lane >> 4, lk = g * 8;
    const size_t head = (size_t)(b * NHEADS + h) * (SEQ * DEPTH);
    const u16* Qh = Q + head + (size_t)qt * 16 * DEPTH;
    const u16* Kh = K + head;
    const u16* Vh = VT + head;            // [64][1024] bf16
    const int wbase = wid << 8;           // wave's contiguous 256-col stripe

    // ---- phase 1: S = K @ Q^T (transposed acc): acc[nt][r] = S[q=lr][wbase+nt*16+4g+r]
    bf16x8 qf0 = *(const bf16x8*)(Qh + lr * DEPTH + lk);
    bf16x8 qf1 = *(const bf16x8*)(Qh + lr * DEPTH + 32 + lk);
    f32x4 acc[16];
    #pragma unroll
    for (int nt = 0; nt < 16; nt++) acc[nt] = (f32x4)0.f;
    #pragma unroll
    for (int nt = 0; nt < 16; nt++) {
        const u16* kp = Kh + (size_t)(wbase + (nt << 4) + lr) * DEPTH + lk;
        bf16x8 k0 = *(const bf16x8*)kp;
        bf16x8 k1 = *(const bf16x8*)(kp + 32);
        acc[nt] = __builtin_amdgcn_mfma_f32_16x16x32_bf16(k0, qf0, acc[nt], 0, 0, 0);
        acc[nt] = __builtin_amdgcn_mfma_f32_16x16x32_bf16(k1, qf1, acc[nt], 0, 0, 0);
    }

    // ---- scale + mask + per-lane max
    const float* mrow = mask + ((size_t)b << 10);
    float mx = -3.0e38f;
    #pragma unroll
    for (int nt = 0; nt < 16; nt++) {
        f32x4 mr = *(const f32x4*)(mrow + wbase + (nt << 4) + 4 * g);
        #pragma unroll
        for (int r = 0; r < 4; r++) {
            acc[nt][r] = acc[nt][r] * 0.125f + mr[r] * -1e9f;
            mx = fmaxf(mx, acc[nt][r]);
        }
    }
    mx = fmaxf(mx, __shfl_xor(mx, 16, 64));
    mx = fmaxf(mx, __shfl_xor(mx, 32, 64));
    if (lane < 16) redm[wid][lr] = mx;
    __syncthreads();
    float gm = fmaxf(fmaxf(redm[0][lr], redm[1][lr]),
                     fmaxf(redm[2][lr], redm[3][lr]));

    // ---- exp + row sum
    float sm = 0.f;
    #pragma unroll
    for (int nt = 0; nt < 16; nt++)
        #pragma unroll
        for (int r = 0; r < 4; r++) {
            float pv = __expf(acc[nt][r] - gm);
            acc[nt][r] = pv;
            sm += pv;
        }
    sm += __shfl_xor(sm, 16, 64);
    sm += __shfl_xor(sm, 32, 64);
    if (lane < 16) reds[wid][lr] = sm;
    __syncthreads();
    float iv = 1.0f / (reds[0][lr] + reds[1][lr] + reds[2][lr] + reds[3][lr]);

    // ---- fused: addw * P -> attn store + lane-local PV
    const int qglob = (qt << 4) + lr;
    const size_t awbase = ((size_t)((b << 10) + qglob)) << 10;
    const size_t aobase = ((size_t)(((b * NHEADS + h) << 10) + qglob)) << 10;
    const u16* vb_base = Vh + (size_t)lr * SEQ;

    f32x4 x[4];
    #pragma unroll
    for (int dt = 0; dt < 4; dt++) x[dt] = (f32x4)0.f;

    #pragma unroll
    for (int nt = 0; nt < 16; nt++) {
        const int kk = wbase + (nt << 4) + 4 * g;
        f32x4 aw = *(const f32x4*)(addw + awbase + kk);
        f32x4 o;
        bf16x4 pa;
        #pragma unroll
        for (int r = 0; r < 4; r++) {
            float v = acc[nt][r] * iv * aw[r];
            o[r] = v;
            pa[r] = (short)f2bf(v);
        }
        *(f32x4*)(attn_out + aobase + kk) = o;
        #pragma unroll
        for (int dt = 0; dt < 4; dt++) {
            bf16x4 vb = *(const bf16x4*)(vb_base + (size_t)(dt << 4) * SEQ + kk);
            x[dt] = mfma_16x16x16_bf16(pa, vb, x[dt]);
        }
    }

    // ---- cross-wave X reduction: partial X[q=4g+r][d=dt*16+lr] per wave
    #pragma unroll
    for (int dt = 0; dt < 4; dt++)
        #pragma unroll
        for (int r = 0; r < 4; r++)
            Xr[wid][4 * g + r][(dt << 4) + lr] = x[dt][r];
    __syncthreads();

    #pragma unroll
    for (int r = 0; r < 4; r++) {
        int q = 4 * g + r, d = (wid << 4) + lr;
        float s = Xr[0][q][d] + Xr[1][q][d] + Xr[2][q][d] + Xr[3][q][d];
        X[((size_t)((b << 10) + (qt << 4) + q)) * DM + (h << 6) + d] = f2bf(s);
    }
}

// ---------------------------------------------------------------- launch
extern "C" void kernel_launch(void* const* d_in, const int* in_sizes, int n_in,
                              void* d_out, int out_size, void* d_ws, size_t ws_size,
                              hipStream_t stream)
{
    const float* q_in = (const float*)d_in[0];
    const float* k_in = (const float*)d_in[1];
    const float* v_in = (const float*)d_in[2];
    const float* mask = (const float*)d_in[3];
    const float* addw = (const float*)d_in[4];
    const float* wq = (const float*)d_in[5];
    const float* bq = (const float*)d_in[6];
    const float* wk = (const float*)d_in[7];
    const float* bk = (const float*)d_in[8];
    const float* wv = (const float*)d_in[9];
    const float* bv = (const float*)d_in[10];
    const float* wo = (const float*)d_in[11];
    const float* bo = (const float*)d_in[12];

    const size_t ACT = (size_t)BATCH * SEQ * DM;   // 4,194,304 elements

    u16* ws = (u16*)d_ws;
    u16* wt  = ws;                    // 4 * 512*512 bf16      (2 MB)
    u16* Qb  = wt + 4 * DM * DM;      // [B,H,S,D] bf16        (8 MB)
    u16* Kb  = Qb + ACT;              // [B,H,S,D] bf16        (8 MB)
    u16* VTb = Kb + ACT;              // [B,H,D,S] bf16        (8 MB)
    u16* Xb  = VTb + ACT;             // [B,S,DM]  bf16        (8 MB)

    float* out0 = (float*)d_out;                         // [B,S,512] f32
    float* attn_out = out0 + ACT;                        // [B,H,S,S] f32 (268 MB)

    transpose512<<<dim3(16, 16, 4), dim3(32, 8), 0, stream>>>(wq, wk, wv, wo, wt);
    qkv_proj<<<dim3(4, 64, 3), 256, 0, stream>>>(q_in, k_in, v_in, wt,
                                                 bq, bk, bv, Qb, Kb, VTb);
    attn_kernel<<<dim3(4096), 256, 0, stream>>>(Qb, Kb, VTb, mask, addw,
                                                attn_out, Xb);
    out_proj<<<dim3(4, 64, 1), 256, 0, stream>>>(Xb, wt + 3 * DM * DM, bo, out0);
}